// Round 14
// baseline (105.784 us; speedup 1.0000x reference)
//
#include <hip/hip_runtime.h>
#include <hip/hip_bf16.h>
#include <math.h>

// Problem dims
#define TOK   8192
#define F_DIM 64
#define U_DIM 128
#define N3    384

// Chebyshev expansion: K = 64 features x 64 coeffs
#define MCH   64
#define KCH   (F_DIM * MCH)      // 4096
#define RCH   6.0f

// Fused GEMM: BM=32 tokens/WG, BK=128 (2 features/step), full K
#define BM    32
#define BK    128
#define NST   (KCH / BK)         // 32
#define ASTR  136

typedef _Float16 h16x8 __attribute__((ext_vector_type(8)));
typedef __bf16   bf16x8 __attribute__((ext_vector_type(8)));
typedef float    f32x4 __attribute__((ext_vector_type(4)));

#define WG_SYNC() do {                                       \
    asm volatile("s_waitcnt lgkmcnt(0)" ::: "memory");       \
    __builtin_amdgcn_s_barrier();                            \
    __builtin_amdgcn_sched_barrier(0);                       \
} while (0)

__device__ __forceinline__ float bflo(unsigned u) { u <<= 16; return __builtin_bit_cast(float, u); }
__device__ __forceinline__ float bfhi(unsigned u) { u &= 0xffff0000u; return __builtin_bit_cast(float, u); }
__device__ __forceinline__ unsigned bfpack(float a, float b) {
    unsigned pa = (unsigned)__builtin_bit_cast(unsigned short, (__bf16)a);
    unsigned pb = (unsigned)__builtin_bit_cast(unsigned short, (__bf16)b);
    return pa | (pb << 16);
}

// ---------------------------------------------------------------------------
// Kernel 1: blocks 0..191 = (mat = bx>>6, f = bx&63): compute feature-f
// Chebyshev coeffs IN-LDS (exact erf-gelu; duplicated per mat — cheap),
// then build Cw[f*64+m][n] = sum_j c[j][m]·W[f*128+j][n] in packed f16
// GEMM layout. Blocks 192..203: pack lin_w/sm_w into MFMA B-frag order.
// ---------------------------------------------------------------------------
__global__ __launch_bounds__(256) void vsn_prep14(
    const float* __restrict__ fw,
    const float* __restrict__ fb,
    const float* __restrict__ elu_w,
    const float* __restrict__ gate_w,
    const float* __restrict__ proj_w,
    const float* __restrict__ lin_w,
    const float* __restrict__ sm_w,
    _Float16* __restrict__ Cw,
    __bf16* __restrict__ linf,
    __bf16* __restrict__ smf)
{
    const int t = threadIdx.x;
    const int bx = blockIdx.x;
    if (bx >= 192) {
        const int xb = bx - 192;
        if (xb < 8) {
#pragma unroll
            for (int i = 0; i < 8; ++i) {
                int idx = xb * 2048 + i * 256 + t;
                int j = idx & 7, l = (idx >> 3) & 63, q = idx >> 9;
                int ks = q >> 3, nj = q & 7;
                int k = ks * 32 + (l >> 4) * 8 + j;
                int n = nj * 16 + (l & 15);
                linf[idx] = (__bf16)lin_w[k * U_DIM + n];
            }
        } else {
            int sb = xb - 8;
#pragma unroll
            for (int i = 0; i < 8; ++i) {
                int idx = sb * 2048 + i * 256 + t;
                int j = idx & 7, l = (idx >> 3) & 63, q = idx >> 9;
                int ks = q >> 2, nj = q & 3;
                int k = ks * 32 + (l >> 4) * 8 + j;
                int n = nj * 16 + (l & 15);
                smf[idx] = (__bf16)sm_w[k * F_DIM + n];
            }
        }
        return;
    }

    __shared__ float ctab[MCH][67];      // 17.2 KB
    __shared__ float g_lds[128][67];     // 34.3 KB
    __shared__ float c_lds[128 * MCH];   // 32 KB
    __shared__ float w_lds[32 * 128];    // 16 KB

    const int f = bx & 63, mat = bx >> 6;
    const float* W = (mat == 0) ? elu_w : (mat == 1 ? gate_w : proj_w);
    const int kg0 = f * 128;

    // phase 1: DCT table
#pragma unroll
    for (int r = 0; r < 16; ++r) {
        int idx = r * 256 + t;
        int m = idx >> 6, i = idx & 63;
        float ang = 3.14159265358979f * (float)m * ((float)i + 0.5f) * (1.0f / 64.0f);
        ctab[m][i] = cosf(ang) * (2.0f / 64.0f) * (m == 0 ? 0.5f : 1.0f);
    }
    __syncthreads();

    // phase 2: g[k][i] = exact gelu at Chebyshev nodes
#pragma unroll 4
    for (int r = 0; r < 32; ++r) {
        int idx = r * 256 + t;
        int k = idx >> 6, i = idx & 63;
        float xi = ctab[1][i] * (RCH * 32.0f);
        float z = fmaf(fw[kg0 + k], xi, fb[kg0 + k]);
        g_lds[k][i] = 0.5f * z * (1.0f + erff(z * 0.70710678f));
    }
    __syncthreads();

    // phase 3: DCT -> c[k][m]
    {
        const int k = t & 127, mh = t >> 7;
#pragma unroll 4
        for (int mm = 0; mm < 32; ++mm) {
            int m = mh * 32 + mm;
            float a = 0.f;
#pragma unroll
            for (int i = 0; i < 64; ++i)
                a = fmaf(g_lds[k][i], ctab[m][i], a);
            c_lds[k * MCH + m] = a;
        }
    }
    __syncthreads();

    // phase 4: build GEMM (R12-validated), write packed f16 layout
    const int n0 = (t & 31) * 4;
    const int mq = t >> 5;
    float acc[8][4];
#pragma unroll
    for (int e = 0; e < 8; ++e)
#pragma unroll
        for (int q = 0; q < 4; ++q) acc[e][q] = 0.f;

    for (int jc = 0; jc < 4; ++jc) {
        __syncthreads();
        {
            const f32x4* src = (const f32x4*)&W[(size_t)(kg0 + jc * 32) * U_DIM];
            f32x4* dst = (f32x4*)w_lds;
#pragma unroll
            for (int r = 0; r < 4; ++r) dst[r * 256 + t] = src[r * 256 + t];
        }
        __syncthreads();

#pragma unroll 4
        for (int jj = 0; jj < 32; ++jj) {
            const int j = jc * 32 + jj;
            f32x4 wv  = *(const f32x4*)&w_lds[jj * 128 + n0];
            f32x4 cv0 = *(const f32x4*)&c_lds[j * MCH + mq * 8];
            f32x4 cv1 = *(const f32x4*)&c_lds[j * MCH + mq * 8 + 4];
#pragma unroll
            for (int e = 0; e < 4; ++e)
#pragma unroll
                for (int q = 0; q < 4; ++q) {
                    acc[e][q]     = fmaf(cv0[e], wv[q], acc[e][q]);
                    acc[e + 4][q] = fmaf(cv1[e], wv[q], acc[e + 4][q]);
                }
        }
    }

    const int kb = mq >> 2;
    const int ko = (mq & 3) * 8;
#pragma unroll
    for (int q = 0; q < 4; ++q) {
        const int ng = mat * U_DIM + n0 + q;
        h16x8 v;
#pragma unroll
        for (int e = 0; e < 8; ++e) v[e] = (_Float16)acc[e][q];
        *(h16x8*)&Cw[(((size_t)(f * 2 + kb) * N3) + ng) * 32 + ko] = v;
    }
}

// ---------------------------------------------------------------------------
// Kernel 2: FUSED Chebyshev GEMM (full K=4096) + epilogue.
// grid 256 WGs (1/CU) x 512 thr (8 waves n-split 48 cols, acc[2][3];
// 2 waves/SIMD). Cw (3.15MB) is L2-resident per XCD (all WGs read same).
// After K-loop: H -> LDS (bf16), barrier, waves 0-1 run epilogue (16 tok
// each): elu/sigmoid -> h2 MFMA (linf) -> gate/resid -> LN -> logits MFMA
// (smf) -> softmax -> out. No Hp roundtrip, no epi launch.
// ---------------------------------------------------------------------------
__global__ __launch_bounds__(512) void vsn_main14(
    const float* __restrict__ x,
    const _Float16* __restrict__ Cw,
    const __bf16* __restrict__ linf,
    const __bf16* __restrict__ smf,
    const float* __restrict__ elu_b,
    const float* __restrict__ lin_b,
    const float* __restrict__ gate_b,
    const float* __restrict__ ln_g,
    const float* __restrict__ ln_b,
    const float* __restrict__ sm_b,
    float* __restrict__ out)
{
    __shared__ float     x_lds[BM][65];        // 8.3 KB
    __shared__ _Float16  a_lds[2][BM][ASTR];   // 17.4 KB
    __shared__ __bf16    H_lds[BM][392];       // 24.5 KB
    __shared__ __bf16    h1_lds[2][16][136];   // 8.7 KB
    __shared__ unsigned  g_lds[2][16][66];     // 8.4 KB
    __shared__ float     p_lds[2][16][132];    // 16.9 KB

    const int t    = threadIdx.x;
    const int wave = t >> 6;
    const int lane = t & 63;
    const int tok0 = blockIdx.x * BM;
    const int nbase = wave * 48;
    const int lr  = lane & 15;
    const int rg  = lane >> 4;
    const int lk8 = rg * 8;

    // stage x (32 tok x 64 feats): 4 elems/thread
#pragma unroll
    for (int i = 0; i < 4; ++i) {
        int idx = i * 512 + t;
        x_lds[idx >> 6][idx & 63] = x[(size_t)tok0 * F_DIM + idx];
    }

    f32x4 acc[2][3];
#pragma unroll
    for (int i = 0; i < 2; ++i)
#pragma unroll
        for (int j = 0; j < 3; ++j)
            acc[i][j] = (f32x4){0.f, 0.f, 0.f, 0.f};

    const int m_a = t >> 4;          // 0..31: token row
    const int q   = t & 15;          // strip: feature q>>3, m0 = (q&7)*8

    // A-tile: T_m(x~), m in [m0, m0+8), feature = st*2 + (q>>3)
    auto cheb_write = [&](int st, int buf) {
        float xr = x_lds[m_a][st * 2 + (q >> 3)];
        float xt = fminf(fmaxf(xr * (1.0f / RCH), -1.0f), 1.0f);
        float x2 = xt + xt;
        float s1 = sqrtf(fmaxf(fmaf(-xt, xt, 1.0f), 0.0f));
        float T2 = fmaf(x2, xt, -1.0f),      S2 = x2 * s1;
        float T4 = fmaf(T2 + T2, T2, -1.0f), S4 = (T2 + T2) * S2;
        float T8 = fmaf(T4 + T4, T4, -1.0f), S8 = (T4 + T4) * S4;
        float T16 = fmaf(T8 + T8, T8, -1.0f),   S16 = (T8 + T8) * S8;
        float T24 = fmaf(T16, T8, -S16 * S8),   S24 = fmaf(S16, T8, T16 * S8);
        float T32 = fmaf(T16 + T16, T16, -1.0f), S32 = (T16 + T16) * S16;
        float T40 = fmaf(T32, T8, -S32 * S8),   S40 = fmaf(S32, T8, T32 * S8);
        float T48 = fmaf(T24 + T24, T24, -1.0f), S48 = (T24 + T24) * S24;
        float T56 = fmaf(T48, T8, -S48 * S8),   S56 = fmaf(S48, T8, T48 * S8);
        const int s3 = q & 7;
        float Ta = (s3 == 0) ? 1.0f : (s3 == 1) ? T8 : (s3 == 2) ? T16 :
                   (s3 == 3) ? T24 : (s3 == 4) ? T32 : (s3 == 5) ? T40 :
                   (s3 == 6) ? T48 : T56;
        float Sa = (s3 == 0) ? 0.0f : (s3 == 1) ? S8 : (s3 == 2) ? S16 :
                   (s3 == 3) ? S24 : (s3 == 4) ? S32 : (s3 == 5) ? S40 :
                   (s3 == 6) ? S48 : S56;
        float v0 = Ta;
        float v1 = fmaf(xt, Ta, -Sa * s1);   // T_{m0+1}
        h16x8 o;
        o[0] = (_Float16)v0; o[1] = (_Float16)v1;
#pragma unroll
        for (int i = 2; i < 8; ++i) {
            float v = fmaf(x2, v1, -v0); v0 = v1; v1 = v;
            o[i] = (_Float16)v;
        }
        *(h16x8*)&a_lds[buf][m_a][q * 8] = o;
    };

    const _Float16* bb = Cw + (nbase + lr) * 32 + lk8;
    auto loadB = [&](int chunk, h16x8 (&dst)[3]) {
        const _Float16* p = bb + (size_t)chunk * (N3 * 32);
#pragma unroll
        for (int j = 0; j < 3; ++j)
            dst[j] = *(const h16x8*)(p + j * 512);
    };

#define MFMA_CHUNK(B, KSI, CUR) do {                                        \
        h16x8 af_[2];                                                       \
        _Pragma("unroll")                                                   \
        for (int i_ = 0; i_ < 2; ++i_)                                      \
            af_[i_] = *(const h16x8*)&a_lds[CUR][i_ * 16 + lr][(KSI) * 32 + lk8]; \
        __builtin_amdgcn_s_setprio(1);                                      \
        _Pragma("unroll")                                                   \
        for (int i_ = 0; i_ < 2; ++i_)                                      \
            _Pragma("unroll")                                               \
            for (int j_ = 0; j_ < 3; ++j_)                                  \
                acc[i_][j_] = __builtin_amdgcn_mfma_f32_16x16x32_f16(       \
                    af_[i_], B[j_], acc[i_][j_], 0, 0, 0);                  \
        __builtin_amdgcn_s_setprio(0);                                      \
    } while (0)

    h16x8 bX[3], bY[3];

    WG_SYNC();                     // x staged
    cheb_write(0, 0);
    loadB(0, bX);

    for (int st = 0; st < NST; ++st) {
        const int cur = st & 1;
        WG_SYNC();                 // a_lds[cur] ready; buf cur^1 free

        loadB(st * 4 + 1, bY);
        if (st + 1 < NST) cheb_write(st + 1, cur ^ 1);
        MFMA_CHUNK(bX, 0, cur);

        loadB(st * 4 + 2, bX);
        MFMA_CHUNK(bY, 1, cur);

        loadB(st * 4 + 3, bY);
        MFMA_CHUNK(bX, 2, cur);

        if (st + 1 < NST) loadB((st + 1) * 4, bX);
        MFMA_CHUNK(bY, 3, cur);
    }
#undef MFMA_CHUNK

    // ---- H -> LDS (C/D: col=lane&15, row=rg*4+r)
#pragma unroll
    for (int i = 0; i < 2; ++i)
#pragma unroll
        for (int j = 0; j < 3; ++j)
#pragma unroll
            for (int r = 0; r < 4; ++r)
                H_lds[i * 16 + rg * 4 + r][nbase + j * 16 + lr]
                    = (__bf16)acc[i][j][r];
    __syncthreads();

    if (wave >= 2) return;   // no further barriers below

    // ================= epilogue (waves 0-1; 16 tokens each) ================
    const int w = wave;
    const float2 eb = *(const float2*)&elu_b[2 * lane];
    const float2 gb = *(const float2*)&gate_b[2 * lane];
#pragma unroll 4
    for (int tk = 0; tk < 16; ++tk) {
        const char* Hrow = (const char*)&H_lds[w * 16 + tk][0];
        unsigned ua = *(const unsigned*)(Hrow + 4 * lane);
        unsigned ug = *(const unsigned*)(Hrow + 256 + 4 * lane);
        unsigned up = *(const unsigned*)(Hrow + 512 + 4 * lane);
        float a0 = bflo(ua), a1 = bfhi(ua);
        float g0 = bflo(ug), g1 = bfhi(ug);
        float p0 = bflo(up), p1 = bfhi(up);
        float e0 = a0 + eb.x, e1 = a1 + eb.y;
        float h10 = (e0 > 0.f) ? e0 : expm1f(e0);
        float h11 = (e1 > 0.f) ? e1 : expm1f(e1);
        *(unsigned*)((char*)&h1_lds[w][tk][0] + 4 * lane) = bfpack(h10, h11);
        float ga  = 1.f / (1.f + __expf(-(g0 + gb.x)));
        float gbv = 1.f / (1.f + __expf(-(g1 + gb.y)));
        g_lds[w][tk][lane] = bfpack(ga, gbv);
        p_lds[w][tk][2 * lane]     = p0;
        p_lds[w][tk][2 * lane + 1] = p1;
    }

    const int c0 = lane & 15;

    // h2 = h1 @ lin_w (32 MFMA; B-frags from global, L2-hot)
    f32x4 acc2[8];
#pragma unroll
    for (int nj = 0; nj < 8; ++nj) acc2[nj] = (f32x4){0.f, 0.f, 0.f, 0.f};
#pragma unroll
    for (int ks = 0; ks < 4; ++ks) {
        bf16x8 af = *(const bf16x8*)&h1_lds[w][c0][ks * 32 + rg * 8];
#pragma unroll
        for (int nj = 0; nj < 8; ++nj) {
            bf16x8 bf = *(const bf16x8*)&linf[((ks * 8 + nj) * 64 + lane) * 8];
            acc2[nj] = __builtin_amdgcn_mfma_f32_16x16x32_bf16(af, bf, acc2[nj], 0, 0, 0);
        }
    }

    float h[8][4];
#pragma unroll
    for (int nj = 0; nj < 8; ++nj) {
        float lb = lin_b[c0 + 16 * nj];
        int colh = (c0 + 16 * nj) >> 1;
        int odd  = c0 & 1;
#pragma unroll
        for (int r = 0; r < 4; ++r) {
            int tokr = rg * 4 + r;
            float h2 = acc2[nj][r] + lb;
            unsigned gu = g_lds[w][tokr][colh];
            float g = odd ? bfhi(gu) : bflo(gu);
            float p = p_lds[w][tokr][c0 + 16 * nj];
            h[nj][r] = fmaf(g, h2, p);
        }
    }

    // LayerNorm per token row (16-lane-group shfl reduce)
    float mu[4], rstd[4];
#pragma unroll
    for (int r = 0; r < 4; ++r) {
        float s = 0.f;
#pragma unroll
        for (int nj = 0; nj < 8; ++nj) s += h[nj][r];
        s += __shfl_xor(s, 1); s += __shfl_xor(s, 2);
        s += __shfl_xor(s, 4); s += __shfl_xor(s, 8);
        mu[r] = s * (1.0f / 128.0f);
        float v = 0.f;
#pragma unroll
        for (int nj = 0; nj < 8; ++nj) {
            float d = h[nj][r] - mu[r];
            v = fmaf(d, d, v);
        }
        v += __shfl_xor(v, 1); v += __shfl_xor(v, 2);
        v += __shfl_xor(v, 4); v += __shfl_xor(v, 8);
        rstd[r] = rsqrtf(v * (1.0f / 128.0f) + 1e-3f);
    }

    // y -> LDS (reuse h1_lds; within-wave ordering via lgkmcnt)
#pragma unroll
    for (int nj = 0; nj < 8; ++nj) {
        int col = c0 + 16 * nj;
        float lg = ln_g[col], lb = ln_b[col];
#pragma unroll
        for (int r = 0; r < 4; ++r) {
            float y = fmaf((h[nj][r] - mu[r]) * rstd[r], lg, lb);
            h1_lds[w][rg * 4 + r][col] = (__bf16)y;
        }
    }

    // logits = y @ sm_w (16 MFMA)
    f32x4 acc3[4];
#pragma unroll
    for (int nj = 0; nj < 4; ++nj) acc3[nj] = (f32x4){0.f, 0.f, 0.f, 0.f};
#pragma unroll
    for (int ks = 0; ks < 4; ++ks) {
        bf16x8 af = *(const bf16x8*)&h1_lds[w][c0][ks * 32 + rg * 8];
#pragma unroll
        for (int nj = 0; nj < 4; ++nj) {
            bf16x8 bf = *(const bf16x8*)&smf[((ks * 4 + nj) * 64 + lane) * 8];
            acc3[nj] = __builtin_amdgcn_mfma_f32_16x16x32_bf16(af, bf, acc3[nj], 0, 0, 0);
        }
    }

    // softmax over 64 features per token + outputs
    float lgt[4][4];
#pragma unroll
    for (int nj = 0; nj < 4; ++nj) {
        float sb = sm_b[c0 + 16 * nj];
#pragma unroll
        for (int r = 0; r < 4; ++r) lgt[nj][r] = acc3[nj][r] + sb;
    }
#pragma unroll
    for (int r = 0; r < 4; ++r) {
        float mx = fmaxf(fmaxf(lgt[0][r], lgt[1][r]), fmaxf(lgt[2][r], lgt[3][r]));
        mx = fmaxf(mx, __shfl_xor(mx, 1)); mx = fmaxf(mx, __shfl_xor(mx, 2));
        mx = fmaxf(mx, __shfl_xor(mx, 4)); mx = fmaxf(mx, __shfl_xor(mx, 8));
        float ex[4], se = 0.f;
#pragma unroll
        for (int nj = 0; nj < 4; ++nj) {
            ex[nj] = __expf(lgt[nj][r] - mx);
            se += ex[nj];
        }
        se += __shfl_xor(se, 1); se += __shfl_xor(se, 2);
        se += __shfl_xor(se, 4); se += __shfl_xor(se, 8);
        float inv = 1.0f / se;
        int tok = tok0 + w * 16 + rg * 4 + r;
#pragma unroll
        for (int nj = 0; nj < 4; ++nj) {
            int f = c0 + 16 * nj;
            float wgt = ex[nj] * inv;
            float xv = x[(size_t)tok * F_DIM + f];
            out[(size_t)tok * F_DIM + f] = xv * wgt;
            out[(size_t)TOK * F_DIM + (size_t)tok * F_DIM + f] = wgt;
        }
    }
}

// ---------------------------------------------------------------------------
extern "C" void kernel_launch(void* const* d_in, const int* in_sizes, int n_in,
                              void* d_out, int out_size, void* d_ws, size_t ws_size,
                              hipStream_t stream)
{
    const float* x      = (const float*)d_in[0];
    const float* fw     = (const float*)d_in[1];
    const float* fb     = (const float*)d_in[2];
    const float* elu_w  = (const float*)d_in[3];
    const float* elu_b  = (const float*)d_in[4];
    const float* lin_w  = (const float*)d_in[5];
    const float* lin_b  = (const float*)d_in[6];
    const float* gate_w = (const float*)d_in[7];
    const float* gate_b = (const float*)d_in[8];
    const float* proj_w = (const float*)d_in[9];
    const float* ln_g   = (const float*)d_in[10];
    const float* ln_b   = (const float*)d_in[11];
    const float* sm_w   = (const float*)d_in[12];
    const float* sm_b   = (const float*)d_in[13];

    // ws: Cw 3.15MB | linf 32KB | smf 16KB
    char* wsb = (char*)d_ws;
    _Float16* Cw   = (_Float16*)wsb;
    __bf16*   linf = (__bf16*)(wsb + (size_t)KCH * N3 * 2);
    __bf16*   smf  = linf + U_DIM * U_DIM;

    vsn_prep14<<<204, 256, 0, stream>>>(fw, fb, elu_w, gate_w, proj_w,
                                        lin_w, sm_w, Cw, linf, smf);
    vsn_main14<<<TOK / BM, 512, 0, stream>>>(x, Cw, linf, smf, elu_b, lin_b,
                                             gate_b, ln_g, ln_b, sm_b,
                                             (float*)d_out);
}